// Round 1
// baseline (53.843 us; speedup 1.0000x reference)
//
#include <hip/hip_runtime.h>

// Continuity loss: for i in {1,2}, j in {0,1,2}:
//   loss -= sum(|X[r,c]*X[r+i,c+j]| * ln|X[r,c]*X[r+i,c+j]|)  over valid r,c
// then loss /= R.  X is (R=8192, C=4096) fp32 row-major. neighbor=3 fixed.
//
// Trick: c*ln(c) = ln2 * c*log2(c) -> accumulate c*__log2f(c) (v_log_f32),
// scale by -ln2/R once at the end.

constexpr int C  = 4096;     // fixed by the problem
constexpr int CQ = C / 4;    // float4 cells per row
constexpr int NBLOCKS  = 4096;
constexpr int NTHREADS = 256;

__device__ __forceinline__ float term_acc(float a, float b, float acc) {
    float c = fabsf(a * b);
    // guard c==0 (0*log->NaN); 1e-30 clamp error is ~1e-28 per term, negligible
    return fmaf(c, __log2f(fmaxf(c, 1e-30f)), acc);
}

// contributions of one neighbor row (offset i): a[k] * b[k+j], j=0..2
__device__ __forceinline__ float row_contrib(const float a[4], const float* __restrict__ pr,
                                             bool interior, float acc) {
    float b[6];
    *reinterpret_cast<float4*>(b) = *reinterpret_cast<const float4*>(pr);
    if (interior) {
        b[4] = pr[4];
        b[5] = pr[5];
#pragma unroll
        for (int k = 0; k < 4; ++k) {
#pragma unroll
            for (int j = 0; j < 3; ++j) {
                acc = term_acc(a[k], b[k + j], acc);
            }
        }
    } else {
        // last float4 of the row: only columns c4+0..c4+3 exist (k+j <= 3)
#pragma unroll
        for (int k = 0; k < 4; ++k) {
#pragma unroll
            for (int j = 0; j < 3; ++j) {
                if (k + j < 4) acc = term_acc(a[k], b[k + j], acc);
            }
        }
    }
    return acc;
}

__global__ __launch_bounds__(NTHREADS) void closs_partial(const float* __restrict__ X,
                                                          float* __restrict__ part, int R) {
    const int total = R * CQ;  // 8M cells, fits int
    float acc = 0.0f;
    for (int idx = blockIdx.x * NTHREADS + threadIdx.x; idx < total;
         idx += gridDim.x * NTHREADS) {
        const int r  = idx >> 10;        // idx / CQ  (CQ = 1024)
        const int cq = idx & (CQ - 1);   // idx % CQ
        const float* p0 = X + ((size_t)r * C + (cq << 2));
        float a[4];
        *reinterpret_cast<float4*>(a) = *reinterpret_cast<const float4*>(p0);
        const bool interior = (cq < CQ - 1);
        if (r + 1 < R) acc = row_contrib(a, p0 + C, interior, acc);
        if (r + 2 < R) acc = row_contrib(a, p0 + 2 * (size_t)C, interior, acc);
    }

    // wave (64-lane) shuffle reduction
#pragma unroll
    for (int off = 32; off > 0; off >>= 1) acc += __shfl_down(acc, off, 64);

    __shared__ float wsum[NTHREADS / 64];
    const int lane = threadIdx.x & 63;
    const int wid  = threadIdx.x >> 6;
    if (lane == 0) wsum[wid] = acc;
    __syncthreads();
    if (threadIdx.x == 0) {
        float s = 0.0f;
#pragma unroll
        for (int w = 0; w < NTHREADS / 64; ++w) s += wsum[w];
        part[blockIdx.x] = s;
    }
}

__global__ __launch_bounds__(256) void closs_final(const float* __restrict__ part,
                                                   float* __restrict__ out, int n,
                                                   double scale) {
    double s = 0.0;
    for (int i = threadIdx.x; i < n; i += 256) s += (double)part[i];
#pragma unroll
    for (int off = 32; off > 0; off >>= 1) s += __shfl_down(s, off, 64);

    __shared__ double wsum[4];
    const int lane = threadIdx.x & 63;
    const int wid  = threadIdx.x >> 6;
    if (lane == 0) wsum[wid] = s;
    __syncthreads();
    if (threadIdx.x == 0) {
        double t = wsum[0] + wsum[1] + wsum[2] + wsum[3];
        out[0] = (float)(t * scale);
    }
}

extern "C" void kernel_launch(void* const* d_in, const int* in_sizes, int n_in,
                              void* d_out, int out_size, void* d_ws, size_t ws_size,
                              hipStream_t stream) {
    const float* X = (const float*)d_in[0];
    const int R = in_sizes[0] / C;  // 8192

    float* part = (float*)d_ws;     // NBLOCKS floats = 16 KiB scratch

    closs_partial<<<NBLOCKS, NTHREADS, 0, stream>>>(X, part, R);

    // loss = -(ln2 / R) * sum(c * log2(c))
    const double scale = -0.69314718055994530942 / (double)R;
    closs_final<<<1, 256, 0, stream>>>(part, (float*)d_out, NBLOCKS, scale);
}

// Round 2
// 46.246 us; speedup vs baseline: 1.1643x; 1.1643x over previous
//
#include <hip/hip_runtime.h>

// Continuity loss, neighbor=3, X = (8192, 4096) fp32 row-major.
// loss = -(1/R) * sum_{i=1,2} sum_{j=0,1,2} |X[r,c]X[r+i,c+j]| ln|X[r,c]X[r+i,c+j]|
//
// Key identity: with u = |x|, w = u*log2(u) (ln2 applied at the end),
//   |ab| ln|ab| = ln2 * (w_a*u_b + u_a*w_b)
// -> one v_log_f32 per ELEMENT instead of one per pair (6x fewer trans ops),
// and per base element the 6 pair terms factor to w_p*Su + u_p*Sw where
// Su/Sw are 3-wide column sums over rows r+1, r+2.

constexpr int C  = 4096;
constexpr int CQ = C / 4;    // 1024 float4 cells per row
constexpr int H  = 32;       // base rows per thread strip
constexpr int NT = 256;

__device__ __forceinline__ void uw6(const float b[6], float u[6], float w[6]) {
#pragma unroll
    for (int k = 0; k < 6; ++k) {
        float a = fabsf(b[k]);
        u[k] = a;
        // clamp guards log2(0); u=0 then gives w = 0 * (-122.9) = 0 (correct limit)
        w[k] = a * __log2f(fmaxf(a, 1e-37f));
    }
}

__global__ __launch_bounds__(NT) void closs_partial(const float* __restrict__ X,
                                                    float* __restrict__ part, int R) {
    const int cq  = (blockIdx.x & 3) * NT + threadIdx.x;  // 0..1023
    const int r0  = (blockIdx.x >> 2) * H;
    const bool halo = (cq < CQ - 1);                      // last quad has no cols c+4,c+5
    const float* base = X + (size_t)r0 * C + (cq << 2);

    float u[3][6], w[3][6], b[6];

    // prologue: rows r0 -> buf0, r0+1 -> buf1 (always in range; R % H == 0, H >= 2)
    {
        *reinterpret_cast<float4*>(b) = *reinterpret_cast<const float4*>(base);
        b[4] = halo ? base[4] : 0.0f;
        b[5] = halo ? base[5] : 0.0f;
        uw6(b, u[0], w[0]);
        const float* p = base + C;
        *reinterpret_cast<float4*>(b) = *reinterpret_cast<const float4*>(p);
        b[4] = halo ? p[4] : 0.0f;
        b[5] = halo ? p[5] : 0.0f;
        uw6(b, u[1], w[1]);
    }

    float acc = 0.0f;
#pragma unroll
    for (int rr = 0; rr < H; ++rr) {
        const int i0 = rr % 3, i1 = (rr + 1) % 3, i2 = (rr + 2) % 3;  // static after unroll
        const int r2 = r0 + rr + 2;
        if (r2 < R) {                       // uniform branch (whole block same strip)
            const float* p = base + (size_t)(rr + 2) * C;
            *reinterpret_cast<float4*>(b) = *reinterpret_cast<const float4*>(p);
            b[4] = halo ? p[4] : 0.0f;
            b[5] = halo ? p[5] : 0.0f;
        } else {
#pragma unroll
            for (int k = 0; k < 6; ++k) b[k] = 0.0f;   // rows >= R contribute nothing
        }
        uw6(b, u[i2], w[i2]);

        // column sums over the two neighbor rows (r+1, r+2)
        float csu[6], csw[6];
#pragma unroll
        for (int k = 0; k < 6; ++k) {
            csu[k] = u[i1][k] + u[i2][k];
            csw[k] = w[i1][k] + w[i2][k];
        }
        // base row r (buf i0): acc += w_p * Su + u_p * Sw over j = 0..2
#pragma unroll
        for (int k = 0; k < 4; ++k) {
            float Su = csu[k] + csu[k + 1] + csu[k + 2];
            float Sw = csw[k] + csw[k + 1] + csw[k + 2];
            acc = fmaf(w[i0][k], Su, fmaf(u[i0][k], Sw, acc));
        }
    }

    // wave shuffle reduction + LDS across 4 waves
#pragma unroll
    for (int off = 32; off > 0; off >>= 1) acc += __shfl_down(acc, off, 64);
    __shared__ float wsum[NT / 64];
    const int lane = threadIdx.x & 63;
    const int wid  = threadIdx.x >> 6;
    if (lane == 0) wsum[wid] = acc;
    __syncthreads();
    if (threadIdx.x == 0) {
        float s = 0.0f;
#pragma unroll
        for (int ww = 0; ww < NT / 64; ++ww) s += wsum[ww];
        part[blockIdx.x] = s;
    }
}

__global__ __launch_bounds__(256) void closs_final(const float* __restrict__ part,
                                                   float* __restrict__ out, int n,
                                                   double scale) {
    double s = 0.0;
    for (int i = threadIdx.x; i < n; i += 256) s += (double)part[i];
#pragma unroll
    for (int off = 32; off > 0; off >>= 1) s += __shfl_down(s, off, 64);
    __shared__ double wsum[4];
    const int lane = threadIdx.x & 63;
    const int wid  = threadIdx.x >> 6;
    if (lane == 0) wsum[wid] = s;
    __syncthreads();
    if (threadIdx.x == 0) {
        double t = wsum[0] + wsum[1] + wsum[2] + wsum[3];
        out[0] = (float)(t * scale);
    }
}

extern "C" void kernel_launch(void* const* d_in, const int* in_sizes, int n_in,
                              void* d_out, int out_size, void* d_ws, size_t ws_size,
                              hipStream_t stream) {
    const float* X = (const float*)d_in[0];
    const int R = in_sizes[0] / C;            // 8192
    const int nblocks = (R / H) * (CQ / NT);  // 256 * 4 = 1024

    float* part = (float*)d_ws;               // nblocks floats = 4 KiB scratch

    closs_partial<<<nblocks, NT, 0, stream>>>(X, part, R);

    // loss = -(ln2 / R) * sum(u*log2-terms)
    const double scale = -0.69314718055994530942 / (double)R;
    closs_final<<<1, 256, 0, stream>>>(part, (float*)d_out, nblocks, scale);
}

// Round 3
// 29.629 us; speedup vs baseline: 1.8172x; 1.5609x over previous
//
#include <hip/hip_runtime.h>

// Continuity loss, neighbor=3, X = (8192, 4096) fp32 row-major.
// loss = -(1/R) * sum_{i=1,2} sum_{j=0,1,2} |X[r,c]X[r+i,c+j]| ln|X[r,c]X[r+i,c+j]|
//
// Identity: u=|x|, w=u*log2(u)  ->  |ab| ln|ab| = ln2*(w_a*u_b + u_a*w_b).
// One v_log_f32 per element-slot; 6 pair terms per base element factor into
// sliding column sums Su/Sw over rows r+1, r+2.
//
// R3 change: explicit 3-deep raw-register prefetch pipeline (rows rr+2..rr+4
// always in flight, unconditional clamped loads) to hide HBM latency.

constexpr int C  = 4096;
constexpr int CQ = C / 4;   // 1024 quads per row
constexpr int H  = 32;      // base rows per strip
constexpr int NT = 256;
constexpr int PF = 3;       // prefetch depth (raw slots)

__global__ __launch_bounds__(NT) void closs_partial(const float* __restrict__ X,
                                                    float* __restrict__ part, int R) {
    const int cq  = (blockIdx.x & 3) * NT + threadIdx.x;  // 0..1023
    const int r0  = (blockIdx.x >> 2) * H;
    const bool halo = (cq < CQ - 1);
    const size_t col = (size_t)cq << 2;

    float raw[PF][6];
    float u[3][6], w[3][6];

    // unconditional, address-clamped row load into a raw slot
    auto load_row = [&](int rr, float* dst) {
        int rabs = r0 + rr;
        int rcl  = rabs < R ? rabs : R - 1;            // block-uniform clamp, no OOB
        const float* p  = X + (size_t)rcl * C + col;
        *reinterpret_cast<float4*>(dst) = *reinterpret_cast<const float4*>(p);
        const float* ph = halo ? p + 4 : X;            // safe dummy addr for last quad
        float2 h = *reinterpret_cast<const float2*>(ph);
        dst[4] = h.x;
        dst[5] = h.y;
    };

    // raw -> (u, w); invalid rows (>= R) and halo-less lanes forced to zero
    auto uw_row = [&](const float* src, float* uu, float* ww, bool valid) {
#pragma unroll
        for (int k = 0; k < 6; ++k) {
            float a = fabsf(src[k]);
            if (k >= 4 && !halo) a = 0.0f;
            if (!valid) a = 0.0f;
            uu[k] = a;
            ww[k] = a * __log2f(fmaxf(a, 1e-37f));     // a==0 -> w==0 (correct limit)
        }
    };

    // prologue: rows 0,1 -> u/w bufs; slots then hold rows 2,3,4
    load_row(0, raw[0]);
    load_row(1, raw[1]);
    load_row(2, raw[2]);
    uw_row(raw[0], u[0], w[0], true);   // r0   < R always
    uw_row(raw[1], u[1], w[1], true);   // r0+1 < R always (H >= 2)
    load_row(3, raw[0]);
    load_row(4, raw[1]);

    float acc = 0.0f;
#pragma unroll
    for (int rr = 0; rr < H; ++rr) {
        const int i0 = rr % 3, i1 = (rr + 1) % 3, i2 = (rr + 2) % 3;  // static
        // consume oldest in-flight row (rr+2), then refill its slot with rr+5
        uw_row(raw[(rr + 2) % PF], u[i2], w[i2], r0 + rr + 2 < R);
        if (rr + 5 <= H + 1) load_row(rr + 5, raw[(rr + 5) % PF]);

        float csu[6], csw[6];
#pragma unroll
        for (int k = 0; k < 6; ++k) {
            csu[k] = u[i1][k] + u[i2][k];
            csw[k] = w[i1][k] + w[i2][k];
        }
#pragma unroll
        for (int k = 0; k < 4; ++k) {
            float Su = csu[k] + csu[k + 1] + csu[k + 2];
            float Sw = csw[k] + csw[k + 1] + csw[k + 2];
            acc = fmaf(w[i0][k], Su, fmaf(u[i0][k], Sw, acc));
        }
    }

    // wave shuffle reduction + LDS across 4 waves
#pragma unroll
    for (int off = 32; off > 0; off >>= 1) acc += __shfl_down(acc, off, 64);
    __shared__ float wsum[NT / 64];
    const int lane = threadIdx.x & 63;
    const int wid  = threadIdx.x >> 6;
    if (lane == 0) wsum[wid] = acc;
    __syncthreads();
    if (threadIdx.x == 0) {
        float s = 0.0f;
#pragma unroll
        for (int ww = 0; ww < NT / 64; ++ww) s += wsum[ww];
        part[blockIdx.x] = s;
    }
}

__global__ __launch_bounds__(256) void closs_final(const float* __restrict__ part,
                                                   float* __restrict__ out, int n,
                                                   double scale) {
    double s = 0.0;
    for (int i = threadIdx.x; i < n; i += 256) s += (double)part[i];
#pragma unroll
    for (int off = 32; off > 0; off >>= 1) s += __shfl_down(s, off, 64);
    __shared__ double wsum[4];
    const int lane = threadIdx.x & 63;
    const int wid  = threadIdx.x >> 6;
    if (lane == 0) wsum[wid] = s;
    __syncthreads();
    if (threadIdx.x == 0) {
        double t = wsum[0] + wsum[1] + wsum[2] + wsum[3];
        out[0] = (float)(t * scale);
    }
}

extern "C" void kernel_launch(void* const* d_in, const int* in_sizes, int n_in,
                              void* d_out, int out_size, void* d_ws, size_t ws_size,
                              hipStream_t stream) {
    const float* X = (const float*)d_in[0];
    const int R = in_sizes[0] / C;            // 8192
    const int nblocks = (R / H) * (CQ / NT);  // 256 * 4 = 1024

    float* part = (float*)d_ws;               // nblocks floats

    closs_partial<<<nblocks, NT, 0, stream>>>(X, part, R);

    const double scale = -0.69314718055994530942 / (double)R;
    closs_final<<<1, 256, 0, stream>>>(part, (float*)d_out, nblocks, scale);
}